// Round 3
// baseline (1685.769 us; speedup 1.0000x reference)
//
#include <hip/hip_runtime.h>

// NodeEdgeProjection: out[b, e, f] = in[b, e/127, f]
//   B=256, N=128 nodes, E=128*127=16256 edges, F=64 features, fp32.
//
// R3: DIAGNOSTIC PROBE (intentionally slow, still correct).
// R0/R1/R2 (nt vs plain, 1 vs 8 chunks/block) are all identical at ~1041 us
// == fill(680) + 361 residue. Ambiguity: kernel at 360us moving 2.13 GB
// (store-miss RFO doubling traffic) vs kernel at 170us (roofline) + ~190us
// hidden harness dispatches. The kernel never appears in top-5 (<674us) so
// its FETCH/WRITE are invisible. Fix: write the output NPASS=6 times with
// asm memory barriers (no store elision). The marginal time per pass is the
// kernel's true write BW, and at >1000us the kernel enters the top-5 where
// its own FETCH_SIZE directly reveals (or acquits) RFO.
//   world (i)  RFO:   dur ~2800us, kernel FETCH ~= WRITE ~= 6.4 GB
//   world (ii) clean: dur ~1700us, kernel WRITE ~= 6.4 GB, FETCH ~= 0

typedef float vfloat4 __attribute__((ext_vector_type(4)));

#define NNODES   128
#define DEG      127            // edges per receiving node (N-1)
#define FEAT4    16             // 64 floats = 16 vfloat4 per row
#define CHUNK4   (DEG * FEAT4)  // 2032 vfloat4 per (b,node) output chunk
#define BLOCK    256
#define CPB      8              // (b,node) chunks per block
#define NPASS    6              // diagnostic: write output 6x

__global__ __launch_bounds__(BLOCK)
void NodeEdgeProjection_5025111736904_kernel(const vfloat4* __restrict__ in,
                                             vfloat4* __restrict__ out) {
    const int t = threadIdx.x;
    const size_t c0 = (size_t)blockIdx.x * CPB;   // first (b*128+node) chunk

    const vfloat4* __restrict__ src = in + c0 * FEAT4 + (t & (FEAT4 - 1));

    vfloat4 v[CPB];
#pragma unroll
    for (int c = 0; c < CPB; ++c)
        v[c] = src[(size_t)c * FEAT4];            // 8 independent loads

    vfloat4* __restrict__ dst = out + c0 * CHUNK4 + t;

    for (int pass = 0; pass < NPASS; ++pass) {
#pragma unroll
        for (int c = 0; c < CPB; ++c) {
#pragma unroll
            for (int k = 0; k < 8; ++k) {         // 2032 = 7*256 + 240
                if (t + k * BLOCK < CHUNK4) {
                    dst[c * CHUNK4 + k * BLOCK] = v[c];
                }
            }
        }
        // Memory clobber: compiler must treat prior stores as observable,
        // so no pass is elided and passes are not merged.
        asm volatile("" ::: "memory");
    }
}

extern "C" void kernel_launch(void* const* d_in, const int* in_sizes, int n_in,
                              void* d_out, int out_size, void* d_ws, size_t ws_size,
                              hipStream_t stream) {
    const vfloat4* in  = (const vfloat4*)d_in[0];   // [256,128,64] fp32
    vfloat4*       out = (vfloat4*)d_out;           // [256,16256,64] fp32

    const int grid = 256 * NNODES / CPB;            // 4096 blocks, 8 chunks each
    NodeEdgeProjection_5025111736904_kernel<<<grid, BLOCK, 0, stream>>>(in, out);
}

// Round 4
// 1047.432 us; speedup vs baseline: 1.6094x; 1.6094x over previous
//
#include <hip/hip_runtime.h>

// NodeEdgeProjection: out[b, e, f] = in[b, e/127, f]
//   B=256, N=128 nodes, E=128*127=16256 edges, F=64 features, fp32.
// Pure broadcast: each 64-float node row replicated 127x.
// 1.065 GB out, 8 MB in.
//
// R4: R3's 6-pass probe proved stores are clean (FETCH~=0, no RFO) and
// steady-state write BW is 7.35 TB/s (145 us/pass marginal). Single-pass
// kernel sits at ~225 us => ~96 us of per-wave-lifetime fixed cost
// (birth load-stall + end-of-kernel store drain + ramp) over 16K short
// waves. This version goes fill-like: 1024 persistent blocks, 32 chunks
// (1.04 MB stores) per block, software-pipelined chunk loads so stores
// stream back-to-back for the whole wave lifetime. 8x fewer waves, 8x
// more stores per wave => fixed cost amortized.

typedef float vfloat4 __attribute__((ext_vector_type(4)));

#define NNODES   128
#define DEG      127            // edges per receiving node (N-1)
#define FEAT4    16             // 64 floats = 16 vfloat4 per row
#define CHUNK4   (DEG * FEAT4)  // 2032 vfloat4 per (b,node) output chunk
#define BLOCK    256
#define CPB      32             // chunks per block -> 1024 blocks, 4/CU

__global__ __launch_bounds__(BLOCK)
void NodeEdgeProjection_5025111736904_kernel(const vfloat4* __restrict__ in,
                                             vfloat4* __restrict__ out) {
    const int t = threadIdx.x;
    const size_t c0 = (size_t)blockIdx.x * CPB;   // first (b*128+node) chunk

    // Per chunk each thread needs exactly one vfloat4 of the source row
    // (p = t + k*256 => p % 16 == t % 16): 16 unique 16B addrs per wave.
    const vfloat4* __restrict__ src = in + c0 * FEAT4 + (t & (FEAT4 - 1));
    vfloat4* __restrict__ dst = out + c0 * CHUNK4 + t;

    vfloat4 cur = src[0];

    for (int c = 0; c < CPB; ++c) {
        // Prefetch next chunk's row fragment; issued before the stores of
        // the current chunk, so the in-order vmcnt wait for it (inserted by
        // the compiler at the next iteration's use) never drains the store
        // stream (wait lands at vmcnt(#outstanding stores)).
        vfloat4 nxt;
        if (c + 1 < CPB) nxt = src[(size_t)(c + 1) * FEAT4];

        vfloat4* __restrict__ d = dst + (size_t)c * CHUNK4;
#pragma unroll
        for (int k = 0; k < 8; ++k) {             // 2032 = 7*256 + 240
            if (t + k * BLOCK < CHUNK4) {
                d[k * BLOCK] = cur;
            }
        }
        cur = nxt;
    }
}

extern "C" void kernel_launch(void* const* d_in, const int* in_sizes, int n_in,
                              void* d_out, int out_size, void* d_ws, size_t ws_size,
                              hipStream_t stream) {
    const vfloat4* in  = (const vfloat4*)d_in[0];   // [256,128,64] fp32
    vfloat4*       out = (vfloat4*)d_out;           // [256,16256,64] fp32

    const int grid = 256 * NNODES / CPB;            // 1024 blocks, 32 chunks each
    NodeEdgeProjection_5025111736904_kernel<<<grid, BLOCK, 0, stream>>>(in, out);
}